// Round 10
// baseline (396.928 us; speedup 1.0000x reference)
//
#include <hip/hip_runtime.h>
#include <hip/hip_bf16.h>
#include <hip/hip_cooperative_groups.h>

#define Bsz 64
#define Wln 512
#define Hd  1024
#define Vc  32000

namespace cg = cooperative_groups;

typedef short v8s __attribute__((ext_vector_type(8)));
typedef float f32x4 __attribute__((ext_vector_type(4)));

__device__ inline unsigned short f2b(float f) {  // round to bf16
  union { float f; unsigned u; } v; v.f = f;
  return (unsigned short)((v.u + 0x8000u) >> 16);
}
__device__ inline float wave_sum(float v) {
  #pragma unroll
  for (int o = 32; o; o >>= 1) v += __shfl_down(v, o);
  return v;
}
__device__ inline float wave_max(float v) {
  #pragma unroll
  for (int o = 32; o; o >>= 1) v = fmaxf(v, __shfl_down(v, o));
  return v;
}
__device__ inline float sigm(float x) { return 1.f / (1.f + expf(-x)); }

__device__ inline v8s cvt_frag(float4 x0, float4 x1) {
  v8s r;
  r[0] = (short)f2b(x0.x); r[1] = (short)f2b(x0.y);
  r[2] = (short)f2b(x0.z); r[3] = (short)f2b(x0.w);
  r[4] = (short)f2b(x1.x); r[5] = (short)f2b(x1.y);
  r[6] = (short)f2b(x1.z); r[7] = (short)f2b(x1.w);
  return r;
}

struct MP {
  const int* input;
  const float *h0, *c0, *enc, *emb;
  const float *W_ih0, *W_hh0, *b_ih0, *b_hh0;
  const float *W_ih1, *W_hh1, *b_ih1, *b_hh1;
  const float *att_w, *att_b, *inW, *inb, *outW, *outb;
  float *out, *out_c, *h1, *h2;
  float *scores, *s_att, *cat, *x1, *x2, *g1, *g2, *pm, *ps;
};

// ---- one 64xN-tile GEMM: C(64 x NS*16 cols at tile bid) = A(64x1024)*B^T + bias
// A staged in LDS bf16 (XOR swizzled); B K-slice preloaded to regs; KS-way
// K-split across 8 waves, LDS reduce. Validated mapping from rounds 5-9.
template<int NS>
__device__ void gemm_tile(const float* __restrict__ A, const float* __restrict__ Ab,
                          int sA, const float* __restrict__ B, int sB,
                          const float* __restrict__ bias, float* __restrict__ out,
                          int N, int bid, char* pool)
{
  constexpr int KS  = 8 / NS;
  constexpr int KSL = 1024 / KS;
  constexpr int NCH = KSL / 32;
  const int tid = threadIdx.x;
  const int w = tid >> 6, lane = tid & 63;
  const int r = lane & 15, q = lane >> 4;
  const int nsub = w % NS, kh = w / NS;
  const int n0 = bid * (NS * 16);

  const float* bp = B + (size_t)(n0 + nsub * 16 + r) * sB + kh * KSL + q * 8;
  float4 breg[NCH][2];
  #pragma unroll
  for (int kk = 0; kk < NCH; ++kk) {
    breg[kk][0] = *(const float4*)(bp + kk * 32);
    breg[kk][1] = *(const float4*)(bp + kk * 32 + 4);
  }

  #pragma unroll
  for (int it = 0; it < 16; ++it) {
    int idx = it * 512 + tid;
    int row = idx >> 7, ch = idx & 127;
    const float* src = A + (size_t)row * sA + ch * 8;
    float4 x0 = *(const float4*)src;
    float4 x1 = *(const float4*)(src + 4);
    if (Ab) {
      const float* s2 = Ab + (size_t)row * sA + ch * 8;
      float4 y0 = *(const float4*)s2;
      float4 y1 = *(const float4*)(s2 + 4);
      x0.x += y0.x; x0.y += y0.y; x0.z += y0.z; x0.w += y0.w;
      x1.x += y1.x; x1.y += y1.y; x1.z += y1.z; x1.w += y1.w;
    }
    *(v8s*)(pool + row * 2048 + ((ch * 16) ^ ((row & 7) << 4))) = cvt_frag(x0, x1);
  }
  __syncthreads();

  f32x4 acc[4] = {{0,0,0,0},{0,0,0,0},{0,0,0,0},{0,0,0,0}};
  const int swz = (r & 7) << 4;
  #pragma unroll
  for (int kk = 0; kk < NCH; ++kk) {
    v8s bf = cvt_frag(breg[kk][0], breg[kk][1]);
    int cb = ((kh * KSL + kk * 32 + q * 8) * 2) ^ swz;
    #pragma unroll
    for (int m = 0; m < 4; ++m) {
      v8s af = *(const v8s*)(pool + (m * 16 + r) * 2048 + cb);
      acc[m] = __builtin_amdgcn_mfma_f32_16x16x32_bf16(af, bf, acc[m], 0, 0, 0);
    }
  }
  __syncthreads();

  float (*red)[64][17] = (float(*)[64][17])pool;
  #pragma unroll
  for (int m = 0; m < 4; ++m)
    #pragma unroll
    for (int rr = 0; rr < 4; ++rr)
      red[w][lane][m * 4 + rr] = acc[m][rr];
  __syncthreads();

  constexpr int COLS = NS * 16;
  #pragma unroll
  for (int it = 0; it < NS * 2; ++it) {
    int e = it * 512 + tid;
    int cc = e % COLS, rowi = e / COLS;
    int ns2 = cc >> 4, lo = cc & 15;
    int idx = ((rowi >> 4) << 2) + (rowi & 3);
    int le  = (((rowi >> 2) & 3) << 4) + lo;
    float s = 0.f;
    #pragma unroll
    for (int j = 0; j < KS; ++j) s += red[ns2 + j * NS][le][idx];
    float bb = bias ? bias[n0 + cc] : 0.f;
    out[(size_t)rowi * N + n0 + cc] = s + bb;
  }
  __syncthreads();
}

__global__ __launch_bounds__(512, 2) void k_mega(MP P)
{
  cg::grid_group grid = cg::this_grid();
  __shared__ __align__(16) char pool[131072];
  __shared__ float w_sh[Wln];
  __shared__ float redA[8], redB[8];
  const int blk = blockIdx.x, tid = threadIdx.x;
  const int w = tid >> 6, lane = tid & 63;

  // ---------- P0: attention scores (2048 waves x 4 rows) + satt/emb ----------
  {
    const float* aw = P.att_w + lane * 16;
    float4 w0 = *(const float4*)aw,       w1 = *(const float4*)(aw + 4);
    float4 w2 = *(const float4*)(aw + 8), w3 = *(const float4*)(aw + 12);
    int gw = blk * 8 + w;
    #pragma unroll
    for (int i = 0; i < 4; ++i) {
      int row = gw * 4 + i;
      const float* p = P.enc + (size_t)row * Hd + lane * 16;
      float4 e0 = *(const float4*)p,       e1 = *(const float4*)(p + 4);
      float4 e2 = *(const float4*)(p + 8), e3 = *(const float4*)(p + 12);
      float s = e0.x*w0.x + e0.y*w0.y + e0.z*w0.z + e0.w*w0.w
              + e1.x*w1.x + e1.y*w1.y + e1.z*w1.z + e1.w*w1.w
              + e2.x*w2.x + e2.y*w2.y + e2.z*w2.z + e2.w*w2.w
              + e3.x*w3.x + e3.y*w3.y + e3.z*w3.z + e3.w*w3.w;
      s = wave_sum(s);
      if (lane == 0) P.scores[row] = s;
    }
    if (blk < Bsz) {
      int b = blk;
      int idx = P.input[b];
      for (int j = tid; j < Hd; j += 512)
        P.cat[b * 2 * Hd + Hd + j] = P.emb[(size_t)idx * Hd + j];
      size_t base = (size_t)(Bsz + b) * Hd;
      float s = 0.f;
      for (int j = tid; j < Hd; j += 512)
        s += P.h0[base + j] * P.c0[base + j] * P.att_w[Hd + j];
      s = wave_sum(s);
      if (lane == 0) redA[w] = s;
      __syncthreads();
      if (tid == 0) {
        float t = 0.f;
        #pragma unroll
        for (int i = 0; i < 8; ++i) t += redA[i];
        P.s_att[b] = t + P.att_b[0];
      }
    }
  }
  grid.sync();

  // ---------- P1: shifted softmax + ctx; block = (b, 256-col quarter) ----------
  {
    int b = blk >> 2, qtr = blk & 3;
    float sa = P.s_att[b];
    const float* sr = P.scores + b * Wln;
    float v = (tid == 0) ? 0.f : sr[tid - 1] + sa;
    float m = wave_max(v);
    if (lane == 0) redA[w] = m;
    __syncthreads();
    float M = redA[0];
    #pragma unroll
    for (int i = 1; i < 8; ++i) M = fmaxf(M, redA[i]);
    float e = expf(v - M);
    float s = wave_sum(e);
    if (lane == 0) redB[w] = s;
    __syncthreads();
    float S = redB[0];
    #pragma unroll
    for (int i = 1; i < 8; ++i) S += redB[i];
    w_sh[tid] = e / S;
    __syncthreads();

    const float* pb = P.enc + (size_t)b * Wln * Hd + qtr * 256 + lane * 4;
    float a0 = 0, a1 = 0, a2 = 0, a3 = 0;
    #pragma unroll 4
    for (int i = 0; i < 64; ++i) {
      int row = w * 64 + i;
      float4 ev = *(const float4*)(pb + (size_t)row * Hd);
      float wi = w_sh[row];
      a0 += wi * ev.x; a1 += wi * ev.y; a2 += wi * ev.z; a3 += wi * ev.w;
    }
    float (*part)[256] = (float(*)[256])pool;
    part[w][lane * 4 + 0] = a0; part[w][lane * 4 + 1] = a1;
    part[w][lane * 4 + 2] = a2; part[w][lane * 4 + 3] = a3;
    __syncthreads();
    if (tid < 256) {
      float s2 = 0.f;
      #pragma unroll
      for (int ww = 0; ww < 8; ++ww) s2 += part[ww][tid];
      P.cat[b * 2 * Hd + qtr * 256 + tid] = s2;
    }
    __syncthreads();
  }
  grid.sync();

  // ---------- P2: input GEMM (K=2048 as two 1024-halves) ----------
  if (blk < 128) {
    if (blk < 64)
      gemm_tile<1>(P.cat, nullptr, 2 * Hd, P.inW, 2 * Hd, P.inb, P.x1, Hd, blk, pool);
    else
      gemm_tile<1>(P.cat + Hd, nullptr, 2 * Hd, P.inW + Hd, 2 * Hd, nullptr, P.x2, Hd, blk - 64, pool);
  }
  grid.sync();

  // ---------- P3: layer-0 gates ----------
  if (blk < 128)
    gemm_tile<2>(P.x1, P.x2, Hd, P.W_ih0, Hd, P.b_ih0, P.g1, 4 * Hd, blk, pool);
  else
    gemm_tile<2>(P.h0, nullptr, Hd, P.W_hh0, Hd, P.b_hh0, P.g2, 4 * Hd, blk - 128, pool);
  grid.sync();

  // ---------- P4: lstm0 ----------
  if (blk < 128) {
    int idx = blk * 512 + tid;
    int b = idx >> 10, j = idx & 1023;
    const float* ga = P.g1 + (size_t)b * 4 * Hd;
    const float* gb = P.g2 + (size_t)b * 4 * Hd;
    float gi = ga[j] + gb[j];
    float gf = ga[Hd + j] + gb[Hd + j];
    float gg = ga[2 * Hd + j] + gb[2 * Hd + j];
    float go = ga[3 * Hd + j] + gb[3 * Hd + j];
    float c = sigm(gf) * P.c0[(size_t)b * Hd + j] + sigm(gi) * tanhf(gg);
    float h = sigm(go) * tanhf(c);
    P.h1[b * Hd + j] = h;
    P.out_c[b * Hd + j] = c;
  }
  grid.sync();

  // ---------- P5: layer-1 gates ----------
  if (blk < 128)
    gemm_tile<2>(P.h1, nullptr, Hd, P.W_ih1, Hd, P.b_ih1, P.g1, 4 * Hd, blk, pool);
  else
    gemm_tile<2>(P.h0 + (size_t)Bsz * Hd, nullptr, Hd, P.W_hh1, Hd, P.b_hh1, P.g2, 4 * Hd, blk - 128, pool);
  grid.sync();

  // ---------- P6: lstm1 ----------
  if (blk < 128) {
    int idx = blk * 512 + tid;
    int b = idx >> 10, j = idx & 1023;
    const float* ga = P.g1 + (size_t)b * 4 * Hd;
    const float* gb = P.g2 + (size_t)b * 4 * Hd;
    float gi = ga[j] + gb[j];
    float gf = ga[Hd + j] + gb[Hd + j];
    float gg = ga[2 * Hd + j] + gb[2 * Hd + j];
    float go = ga[3 * Hd + j] + gb[3 * Hd + j];
    float c = sigm(gf) * P.c0[(size_t)(Bsz + b) * Hd + j] + sigm(gi) * tanhf(gg);
    float h = sigm(go) * tanhf(c);
    P.h2[b * Hd + j] = h;
    P.out_c[(size_t)(Bsz + b) * Hd + j] = c;
  }
  grid.sync();

  // ---------- P7: logits GEMM (500 tiles over 256 blocks) ----------
  for (int tile = blk; tile < 500; tile += 256)
    gemm_tile<4>(P.h2, nullptr, Hd, P.outW, Hd, P.outb, P.out, Vc, tile, pool);
  grid.sync();

  // ---------- P8: log-softmax partials; block = (b, 8000-col chunk) ----------
  {
    int b = blk >> 2, qc = blk & 3;
    const float* row = P.out + (size_t)b * Vc + qc * 8000;
    float m = -1e30f;
    for (int j = tid * 4; j < 8000; j += 2048) {
      float4 v = *(const float4*)(row + j);
      m = fmaxf(m, fmaxf(fmaxf(v.x, v.y), fmaxf(v.z, v.w)));
    }
    m = wave_max(m);
    if (lane == 0) redA[w] = m;
    __syncthreads();
    float M = redA[0];
    #pragma unroll
    for (int i = 1; i < 8; ++i) M = fmaxf(M, redA[i]);
    float s = 0.f;
    for (int j = tid * 4; j < 8000; j += 2048) {
      float4 v = *(const float4*)(row + j);
      s += expf(v.x - M) + expf(v.y - M) + expf(v.z - M) + expf(v.w - M);
    }
    s = wave_sum(s);
    if (lane == 0) redB[w] = s;
    __syncthreads();
    float S = redB[0];
    #pragma unroll
    for (int i = 1; i < 8; ++i) S += redB[i];
    if (tid == 0) { P.pm[blk] = M; P.ps[blk] = S; }
  }
  grid.sync();

  // ---------- P9: combine partials, subtract lse ----------
  {
    int b = blk >> 2, qc = blk & 3;
    float M = P.pm[b * 4];
    #pragma unroll
    for (int i = 1; i < 4; ++i) M = fmaxf(M, P.pm[b * 4 + i]);
    float S = 0.f;
    #pragma unroll
    for (int i = 0; i < 4; ++i) S += P.ps[b * 4 + i] * expf(P.pm[b * 4 + i] - M);
    float lse = M + logf(S);
    float* row = P.out + (size_t)b * Vc + qc * 8000;
    for (int j = tid * 4; j < 8000; j += 2048) {
      float4 v = *(const float4*)(row + j);
      v.x -= lse; v.y -= lse; v.z -= lse; v.w -= lse;
      *(float4*)(row + j) = v;
    }
  }
}

extern "C" void kernel_launch(void* const* d_in, const int* in_sizes, int n_in,
                              void* d_out, int out_size, void* d_ws, size_t ws_size,
                              hipStream_t stream)
{
  MP P;
  P.input = (const int*)d_in[0];
  P.h0    = (const float*)d_in[1];
  P.c0    = (const float*)d_in[2];
  P.enc   = (const float*)d_in[3];
  P.emb   = (const float*)d_in[4];
  P.W_ih0 = (const float*)d_in[5];
  P.W_hh0 = (const float*)d_in[6];
  P.b_ih0 = (const float*)d_in[7];
  P.b_hh0 = (const float*)d_in[8];
  P.W_ih1 = (const float*)d_in[9];
  P.W_hh1 = (const float*)d_in[10];
  P.b_ih1 = (const float*)d_in[11];
  P.b_hh1 = (const float*)d_in[12];
  P.att_w = (const float*)d_in[13];
  P.att_b = (const float*)d_in[14];
  P.inW   = (const float*)d_in[15];
  P.inb   = (const float*)d_in[16];
  P.outW  = (const float*)d_in[17];
  P.outb  = (const float*)d_in[18];

  float* out = (float*)d_out;
  P.out   = out;
  float* out_h = out + (size_t)Bsz * Vc;
  P.out_c = out_h + 2 * Bsz * Hd;
  P.h1 = out_h;
  P.h2 = out_h + Bsz * Hd;

  // scratch in d_ws (ws_size is ~512 MiB per harness fill evidence; we use <6 MB)
  char* ws = (char*)d_ws;
  P.g1     = (float*)(ws + 0);          // 64x4096
  P.g2     = (float*)(ws + 1048576);    // 64x4096
  P.cat    = (float*)(ws + 2097152);    // 64x2048 [ctx|emb]
  P.x1     = (float*)(ws + 2621440);    // 64x1024
  P.x2     = (float*)(ws + 2883584);    // 64x1024
  P.scores = (float*)(ws + 3145728);    // 64x512
  P.s_att  = (float*)(ws + 3276800);    // 64
  P.pm     = (float*)(ws + 3277824);    // 256
  P.ps     = (float*)(ws + 3278848);    // 256

  void* args[] = { (void*)&P };
  hipLaunchCooperativeKernel((const void*)k_mega, dim3(256), dim3(512), args, 0, stream);
}

// Round 11
// 142.324 us; speedup vs baseline: 2.7889x; 2.7889x over previous
//
#include <hip/hip_runtime.h>
#include <hip/hip_bf16.h>

#define Bsz 64
#define Wln 512
#define Hd  1024
#define Vc  32000

typedef short v8s __attribute__((ext_vector_type(8)));
typedef float f32x4 __attribute__((ext_vector_type(4)));

__device__ inline unsigned short f2b(float f) {  // round to bf16
  union { float f; unsigned u; } v; v.f = f;
  return (unsigned short)((v.u + 0x8000u) >> 16);
}
__device__ inline float wave_sum(float v) {
  #pragma unroll
  for (int o = 32; o; o >>= 1) v += __shfl_down(v, o);
  return v;
}
__device__ inline float wave_max(float v) {
  #pragma unroll
  for (int o = 32; o; o >>= 1) v = fmaxf(v, __shfl_down(v, o));
  return v;
}
__device__ inline float sigm(float x) { return 1.f / (1.f + expf(-x)); }

__device__ inline v8s cvt_frag(float4 x0, float4 x1) {
  v8s r;
  r[0] = (short)f2b(x0.x); r[1] = (short)f2b(x0.y);
  r[2] = (short)f2b(x0.z); r[3] = (short)f2b(x0.w);
  r[4] = (short)f2b(x1.x); r[5] = (short)f2b(x1.y);
  r[6] = (short)f2b(x1.z); r[7] = (short)f2b(x1.w);
  return r;
}

// stage 64 x 1024 f32 (row stride sA) -> LDS bf16, XOR-swizzled
__device__ inline void stage_A(const float* __restrict__ A, int sA,
                               char* pool, int tid) {
  #pragma unroll
  for (int it = 0; it < 16; ++it) {
    int idx = it * 512 + tid;
    int row = idx >> 7, ch = idx & 127;
    const float* src = A + (size_t)row * sA + ch * 8;
    float4 x0 = *(const float4*)src;
    float4 x1 = *(const float4*)(src + 4);
    *(v8s*)(pool + row * 2048 + ((ch * 16) ^ ((row & 7) << 4))) = cvt_frag(x0, x1);
  }
}

// ---- fused: attention scores (blocks 0..8191) + s_att/emb gather (8192..8255) ----
__global__ __launch_bounds__(256) void k_scores_satt(
    const float* __restrict__ enc, const float* __restrict__ att_w,
    const float* __restrict__ h0, const float* __restrict__ c0,
    const float* __restrict__ att_b, const int* __restrict__ input,
    const float* __restrict__ emb,
    float* __restrict__ scores, float* __restrict__ s_att,
    float* __restrict__ cat)
{
  __shared__ float red[4];
  int t = threadIdx.x;
  if (blockIdx.x < 8192) {
    int row = blockIdx.x * 4 + (t >> 6);
    int lane = t & 63;
    const float* p = enc + (size_t)row * Hd + lane * 16;
    const float* w = att_w + lane * 16;
    float s = 0.f;
    #pragma unroll
    for (int c = 0; c < 4; ++c) {
      float4 e = *(const float4*)(p + c * 4);
      float4 ww = *(const float4*)(w + c * 4);
      s += e.x * ww.x + e.y * ww.y + e.z * ww.z + e.w * ww.w;
    }
    s = wave_sum(s);
    if (lane == 0) scores[row] = s;     // s_att added in ctx softmax
  } else {
    int b = blockIdx.x - 8192;
    int idx = input[b];
    for (int j = t; j < Hd; j += 256)
      cat[b * 2 * Hd + Hd + j] = emb[(size_t)idx * Hd + j];
    size_t base = (size_t)(Bsz + b) * Hd;
    float s = 0.f;
    for (int j = t; j < Hd; j += 256)
      s += h0[base + j] * c0[base + j] * att_w[Hd + j];
    s = wave_sum(s);
    if ((t & 63) == 0) red[t >> 6] = s;
    __syncthreads();
    if (t == 0) s_att[b] = red[0] + red[1] + red[2] + red[3] + att_b[0];
  }
}

// ---- merged softmax+ctx: block = (b, 256-col quarter); small LDS, high occ ----
__global__ __launch_bounds__(512) void k_ctx(
    const float* __restrict__ scores, const float* __restrict__ s_att,
    const float* __restrict__ enc, float* __restrict__ cat)
{
  __shared__ float w_sh[Wln];
  __shared__ float part[8][256];
  __shared__ float redA[8], redB[8];
  int b = blockIdx.x >> 2, qtr = blockIdx.x & 3;
  int tid = threadIdx.x, w = tid >> 6, lane = tid & 63;
  float sa = s_att[b];
  const float* sr = scores + b * Wln;
  float v = (tid == 0) ? 0.f : sr[tid - 1] + sa;
  float m = wave_max(v);
  if (lane == 0) redA[w] = m;
  __syncthreads();
  float M = redA[0];
  #pragma unroll
  for (int i = 1; i < 8; ++i) M = fmaxf(M, redA[i]);
  float e = expf(v - M);
  float s = wave_sum(e);
  if (lane == 0) redB[w] = s;
  __syncthreads();
  float S = redB[0];
  #pragma unroll
  for (int i = 1; i < 8; ++i) S += redB[i];
  w_sh[tid] = e / S;
  __syncthreads();

  const float* pb = enc + (size_t)b * Wln * Hd + qtr * 256 + lane * 4;
  float a0 = 0, a1 = 0, a2 = 0, a3 = 0;
  #pragma unroll 4
  for (int i = 0; i < 64; ++i) {
    int row = w * 64 + i;
    float4 ev = *(const float4*)(pb + (size_t)row * Hd);
    float wi = w_sh[row];
    a0 += wi * ev.x; a1 += wi * ev.y; a2 += wi * ev.z; a3 += wi * ev.w;
  }
  part[w][lane * 4 + 0] = a0; part[w][lane * 4 + 1] = a1;
  part[w][lane * 4 + 2] = a2; part[w][lane * 4 + 3] = a3;
  __syncthreads();
  if (tid < 256) {
    float s2 = 0.f;
    #pragma unroll
    for (int ww = 0; ww < 8; ++ww) s2 += part[ww][tid];
    cat[b * 2 * Hd + qtr * 256 + tid] = s2;
  }
}

// ---- input GEMM: x(64x1024) = cat(64x2048)@inW^T + inb; two-phase K staging ----
__global__ __launch_bounds__(512) void k_input_gemm(
    const float* __restrict__ cat, const float* __restrict__ inW,
    const float* __restrict__ inb, float* __restrict__ x)
{
  __shared__ __align__(16) char pool[131072];
  const int tid = threadIdx.x;
  const int w = tid >> 6, lane = tid & 63;
  const int r = lane & 15, q = lane >> 4;
  const int kh = w;                     // NS=1: KS=8, KSL=128 per phase
  const int n0 = blockIdx.x * 16;

  f32x4 acc[4] = {{0,0,0,0},{0,0,0,0},{0,0,0,0},{0,0,0,0}};
  #pragma unroll
  for (int p = 0; p < 2; ++p) {
    const float* bp = inW + (size_t)(n0 + r) * 2048 + p * 1024 + kh * 128 + q * 8;
    float4 breg[4][2];
    #pragma unroll
    for (int kk = 0; kk < 4; ++kk) {
      breg[kk][0] = *(const float4*)(bp + kk * 32);
      breg[kk][1] = *(const float4*)(bp + kk * 32 + 4);
    }
    stage_A(cat + p * 1024, 2048, pool, tid);
    __syncthreads();
    const int swz = (r & 7) << 4;
    #pragma unroll
    for (int kk = 0; kk < 4; ++kk) {
      v8s bf = cvt_frag(breg[kk][0], breg[kk][1]);
      int cb = ((kh * 128 + kk * 32 + q * 8) * 2) ^ swz;
      #pragma unroll
      for (int m = 0; m < 4; ++m) {
        v8s af = *(const v8s*)(pool + (m * 16 + r) * 2048 + cb);
        acc[m] = __builtin_amdgcn_mfma_f32_16x16x32_bf16(af, bf, acc[m], 0, 0, 0);
      }
    }
    __syncthreads();
  }

  float (*red)[64][17] = (float(*)[64][17])pool;
  #pragma unroll
  for (int m = 0; m < 4; ++m)
    #pragma unroll
    for (int rr = 0; rr < 4; ++rr)
      red[w][lane][m * 4 + rr] = acc[m][rr];
  __syncthreads();

  #pragma unroll
  for (int it = 0; it < 2; ++it) {
    int e = it * 512 + tid;              // [0, 1024): 64 rows x 16 cols
    int cc = e & 15, rowi = e >> 4;
    int idx = ((rowi >> 4) << 2) + (rowi & 3);
    int le  = (((rowi >> 2) & 3) << 4) + cc;
    float s = 0.f;
    #pragma unroll
    for (int j = 0; j < 8; ++j) s += red[j][le][idx];
    x[(size_t)rowi * Hd + n0 + cc] = s + inb[n0 + cc];
  }
}

// ---- fused gate GEMM + LSTM: block = 8 j-cols x 4 gates (gate-interleaved) ----
// g[:, gate*H + j] = xA@W_ih^T + hA@W_hh^T + biases, then LSTM elementwise.
__global__ __launch_bounds__(512) void k_gate_lstm(
    const float* __restrict__ xA, const float* __restrict__ hA,
    const float* __restrict__ W_ih, const float* __restrict__ W_hh,
    const float* __restrict__ b_ih, const float* __restrict__ b_hh,
    const float* __restrict__ c0,
    float* __restrict__ out_h, float* __restrict__ out_c)
{
  __shared__ __align__(16) char pool[131072];
  const int tid = threadIdx.x;
  const int w = tid >> 6, lane = tid & 63;
  const int r = lane & 15, q = lane >> 4;
  const int nsub = w & 1, kh = w >> 1;   // NS=2: KS=4, KSL=256 per phase
  const int cc_w = nsub * 16 + r;        // col-in-block [0,32)
  const int gate = cc_w >> 3, jl = cc_w & 7;
  const size_t Brow = (size_t)(gate * Hd + blockIdx.x * 8 + jl);

  f32x4 acc[4] = {{0,0,0,0},{0,0,0,0},{0,0,0,0},{0,0,0,0}};
  const float* Amat[2] = { xA, hA };
  const float* Wmat[2] = { W_ih, W_hh };
  #pragma unroll
  for (int p = 0; p < 2; ++p) {
    const float* bp = Wmat[p] + Brow * Hd + kh * 256 + q * 8;
    float4 breg[8][2];
    #pragma unroll
    for (int kk = 0; kk < 8; ++kk) {
      breg[kk][0] = *(const float4*)(bp + kk * 32);
      breg[kk][1] = *(const float4*)(bp + kk * 32 + 4);
    }
    stage_A(Amat[p], Hd, pool, tid);
    __syncthreads();
    const int swz = (r & 7) << 4;
    #pragma unroll
    for (int kk = 0; kk < 8; ++kk) {
      v8s bf = cvt_frag(breg[kk][0], breg[kk][1]);
      int cb = ((kh * 256 + kk * 32 + q * 8) * 2) ^ swz;
      #pragma unroll
      for (int m = 0; m < 4; ++m) {
        v8s af = *(const v8s*)(pool + (m * 16 + r) * 2048 + cb);
        acc[m] = __builtin_amdgcn_mfma_f32_16x16x32_bf16(af, bf, acc[m], 0, 0, 0);
      }
    }
    __syncthreads();
  }

  float (*red)[64][17] = (float(*)[64][17])pool;
  #pragma unroll
  for (int m = 0; m < 4; ++m)
    #pragma unroll
    for (int rr = 0; rr < 4; ++rr)
      red[w][lane][m * 4 + rr] = acc[m][rr];
  __syncthreads();

  // epilogue: thread = (b, jl2); gather all 4 gates from LDS, run LSTM
  int b = tid >> 3, jl2 = tid & 7;
  int jg = blockIdx.x * 8 + jl2;
  float gv[4];
  #pragma unroll
  for (int g2 = 0; g2 < 4; ++g2) {
    int cc = g2 * 8 + jl2;
    int ns2 = cc >> 4, lo = cc & 15;
    int idx = ((b >> 4) << 2) + (b & 3);
    int le  = (((b >> 2) & 3) << 4) + lo;
    float s = 0.f;
    #pragma unroll
    for (int j = 0; j < 4; ++j) s += red[ns2 + j * 2][le][idx];
    gv[g2] = s + b_ih[g2 * Hd + jg] + b_hh[g2 * Hd + jg];
  }
  float c = sigm(gv[1]) * c0[(size_t)b * Hd + jg] + sigm(gv[0]) * tanhf(gv[2]);
  float h = sigm(gv[3]) * tanhf(c);
  out_h[(size_t)b * Hd + jg] = h;
  out_c[(size_t)b * Hd + jg] = c;
}

// ---- logits GEMM: C(64 x 32000) = h2 @ outW^T + outb; NS=4 tile ----
__global__ __launch_bounds__(512) void k_logits(
    const float* __restrict__ A, const float* __restrict__ B,
    const float* __restrict__ bias, float* __restrict__ out)
{
  __shared__ __align__(16) char pool[131072];
  const int tid = threadIdx.x;
  const int w = tid >> 6, lane = tid & 63;
  const int r = lane & 15, q = lane >> 4;
  const int nsub = w & 3, kh = w >> 2;    // NS=4: KS=2, KSL=512
  const int n0 = blockIdx.x * 64;

  const float* bp = B + (size_t)(n0 + nsub * 16 + r) * Hd + kh * 512 + q * 8;
  float4 breg[16][2];
  #pragma unroll
  for (int kk = 0; kk < 16; ++kk) {
    breg[kk][0] = *(const float4*)(bp + kk * 32);
    breg[kk][1] = *(const float4*)(bp + kk * 32 + 4);
  }
  stage_A(A, Hd, pool, tid);
  __syncthreads();

  f32x4 acc[4] = {{0,0,0,0},{0,0,0,0},{0,0,0,0},{0,0,0,0}};
  const int swz = (r & 7) << 4;
  #pragma unroll
  for (int kk = 0; kk < 16; ++kk) {
    v8s bf = cvt_frag(breg[kk][0], breg[kk][1]);
    int cb = ((kh * 512 + kk * 32 + q * 8) * 2) ^ swz;
    #pragma unroll
    for (int m = 0; m < 4; ++m) {
      v8s af = *(const v8s*)(pool + (m * 16 + r) * 2048 + cb);
      acc[m] = __builtin_amdgcn_mfma_f32_16x16x32_bf16(af, bf, acc[m], 0, 0, 0);
    }
  }
  __syncthreads();

  float (*red)[64][17] = (float(*)[64][17])pool;
  #pragma unroll
  for (int m = 0; m < 4; ++m)
    #pragma unroll
    for (int rr = 0; rr < 4; ++rr)
      red[w][lane][m * 4 + rr] = acc[m][rr];
  __syncthreads();

  #pragma unroll
  for (int it = 0; it < 8; ++it) {
    int e = it * 512 + tid;               // [0, 4096): 64 rows x 64 cols
    int cc = e & 63, rowi = e >> 6;
    int ns2 = cc >> 4, lo = cc & 15;
    int idx = ((rowi >> 4) << 2) + (rowi & 3);
    int le  = (((rowi >> 2) & 3) << 4) + lo;
    float s = red[ns2][le][idx] + red[ns2 + 4][le][idx];
    out[(size_t)rowi * Vc + n0 + cc] = s + bias[n0 + cc];
  }
}

// ---- log-softmax partials: block = (b, 8000-col chunk) ----
__global__ __launch_bounds__(512) void k_lsm_part(
    const float* __restrict__ lg, float* __restrict__ pm, float* __restrict__ ps)
{
  __shared__ float redA[8], redB[8];
  int b = blockIdx.x >> 2, qc = blockIdx.x & 3;
  int tid = threadIdx.x, w = tid >> 6, lane = tid & 63;
  const float* row = lg + (size_t)b * Vc + qc * 8000;
  float m = -1e30f;
  for (int j = tid * 4; j < 8000; j += 2048) {
    float4 v = *(const float4*)(row + j);
    m = fmaxf(m, fmaxf(fmaxf(v.x, v.y), fmaxf(v.z, v.w)));
  }
  m = wave_max(m);
  if (lane == 0) redA[w] = m;
  __syncthreads();
  float M = redA[0];
  #pragma unroll
  for (int i = 1; i < 8; ++i) M = fmaxf(M, redA[i]);
  float s = 0.f;
  for (int j = tid * 4; j < 8000; j += 2048) {
    float4 v = *(const float4*)(row + j);
    s += expf(v.x - M) + expf(v.y - M) + expf(v.z - M) + expf(v.w - M);
  }
  s = wave_sum(s);
  if (lane == 0) redB[w] = s;
  __syncthreads();
  if (tid == 0) {
    float S = redB[0];
    #pragma unroll
    for (int i = 1; i < 8; ++i) S += redB[i];
    pm[blockIdx.x] = M; ps[blockIdx.x] = S;
  }
}

// ---- log-softmax subtract ----
__global__ __launch_bounds__(512) void k_lsm_sub(
    float* __restrict__ lg, const float* __restrict__ pm, const float* __restrict__ ps)
{
  int b = blockIdx.x >> 2, qc = blockIdx.x & 3;
  int tid = threadIdx.x;
  float M = pm[b * 4];
  #pragma unroll
  for (int i = 1; i < 4; ++i) M = fmaxf(M, pm[b * 4 + i]);
  float S = 0.f;
  #pragma unroll
  for (int i = 0; i < 4; ++i) S += ps[b * 4 + i] * expf(pm[b * 4 + i] - M);
  float lse = M + logf(S);
  float* row = lg + (size_t)b * Vc + qc * 8000;
  for (int j = tid * 4; j < 8000; j += 2048) {
    float4 v = *(const float4*)(row + j);
    v.x -= lse; v.y -= lse; v.z -= lse; v.w -= lse;
    *(float4*)(row + j) = v;
  }
}

extern "C" void kernel_launch(void* const* d_in, const int* in_sizes, int n_in,
                              void* d_out, int out_size, void* d_ws, size_t ws_size,
                              hipStream_t stream)
{
  const int*   input = (const int*)d_in[0];
  const float* h0    = (const float*)d_in[1];
  const float* c0    = (const float*)d_in[2];
  const float* enc   = (const float*)d_in[3];
  const float* emb   = (const float*)d_in[4];
  const float* W_ih0 = (const float*)d_in[5];
  const float* W_hh0 = (const float*)d_in[6];
  const float* b_ih0 = (const float*)d_in[7];
  const float* b_hh0 = (const float*)d_in[8];
  const float* W_ih1 = (const float*)d_in[9];
  const float* W_hh1 = (const float*)d_in[10];
  const float* b_ih1 = (const float*)d_in[11];
  const float* b_hh1 = (const float*)d_in[12];
  const float* att_w = (const float*)d_in[13];
  const float* att_b = (const float*)d_in[14];
  const float* inW   = (const float*)d_in[15];
  const float* inb   = (const float*)d_in[16];
  const float* outW  = (const float*)d_in[17];
  const float* outb  = (const float*)d_in[18];
  float* out = (float*)d_out;

  char* ws = (char*)d_ws;
  float* cat    = (float*)(ws + 0);          // 64x2048 [ctx | emb]
  float* x      = (float*)(ws + 524288);     // 64x1024
  float* scores = (float*)(ws + 786432);     // 64x512
  float* s_att  = (float*)(ws + 917504);     // 64
  float* pm     = (float*)(ws + 918528);     // 256
  float* ps     = (float*)(ws + 919552);     // 256

  float* out_h = out + (size_t)Bsz * Vc;     // [2,B,H]
  float* out_c = out_h + 2 * Bsz * Hd;       // [2,B,H]
  float* h1 = out_h;
  float* h2 = out_h + Bsz * Hd;

  k_scores_satt<<<8256, 256, 0, stream>>>(enc, att_w, h0, c0, att_b, input, emb,
                                          scores, s_att, cat);
  k_ctx<<<Bsz * 4, 512, 0, stream>>>(scores, s_att, enc, cat);
  k_input_gemm<<<64, 512, 0, stream>>>(cat, inW, inb, x);
  k_gate_lstm<<<128, 512, 0, stream>>>(x, h0, W_ih0, W_hh0, b_ih0, b_hh0,
                                       c0, h1, out_c);
  k_gate_lstm<<<128, 512, 0, stream>>>(h1, h0 + (size_t)Bsz * Hd, W_ih1, W_hh1,
                                       b_ih1, b_hh1, c0 + (size_t)Bsz * Hd,
                                       h2, out_c + Bsz * Hd);
  k_logits<<<500, 512, 0, stream>>>(h2, outW, outb, out);
  k_lsm_part<<<256, 512, 0, stream>>>(out, pm, ps);
  k_lsm_sub<<<256, 512, 0, stream>>>(out, pm, ps);
}